// Round 9
// baseline (1249.213 us; speedup 1.0000x reference)
//
#include <hip/hip_runtime.h>

typedef unsigned short u16;
typedef unsigned char  u8;
typedef signed char    s8;
typedef __bf16 bf16x8 __attribute__((ext_vector_type(8)));
typedef int    i32x4  __attribute__((ext_vector_type(4)));

#define T_STEPS 128
#define S2STR   776    // stage2 output row stride (u16): 768 + 8 pad

// ---- ws BYTE layout ----
// PK1  @      0 : 16 ft x 5 kt x 1024 =  81920  (Wm0 -> i8 A-frags, 16x16x64)
// PK2  @  81920 : 48 x 5 x 1024      = 245760  (Wf10|Wf20|Wh0)
// PK3  @ 327680 : 16 x 5 x 1024      =  81920  (Wm1, rows permuted)
// BIAS @ 409600 : 1288 f32 (B1[256] B2[768] B3[256] BS[8])
// HW   @ 414752 : 2048 bf16 (head weights [o][k])
//
// Quant: weights w_q = rne(w * 2032) (= w/0.0625*127), |w|<=1/sqrt(260)<0.0625.
// Activations: cu/c region scale 127 (|v|<1); sn/meas/supd region scale 127/480 (v/60*127/8).
// Epilogue: pre = accA*SA + accB*SB + bias, SA = 0.0625/127^2, SB = 0.5/127^2.

__device__ __forceinline__ float bf2f(u16 h) {
  union { unsigned int u; float f; } v; v.u = ((unsigned int)h) << 16; return v.f;
}
__device__ __forceinline__ u16 f2bf(float f) {
  union { float f; unsigned int u; } v; v.f = f;
  unsigned int u = v.u;
  return (u16)((u + 0x7fffu + ((u >> 16) & 1u)) >> 16);
}
__device__ __forceinline__ unsigned int pack2(float a, float b) {
  return (unsigned int)f2bf(a) | ((unsigned int)f2bf(b) << 16);
}
__device__ __forceinline__ float clampf(float x, float lo, float hi) {
  return fmaxf(lo, fminf(x, hi));   // NaN-absorbing insurance
}
__device__ __forceinline__ float tanh_fast(float x) {
  float e = __expf(2.0f * x);
  return 1.0f - 2.0f * __builtin_amdgcn_rcpf(e + 1.0f);
}
__device__ __forceinline__ int q8(float v, float s) {
  int q = __float2int_rn(v * s);
  return max(-127, min(127, q));
}
__device__ __forceinline__ unsigned int pack4q(float a, float b, float c, float d, float s) {
  return (unsigned int)(q8(a,s) & 255) | ((unsigned int)(q8(b,s) & 255) << 8) |
         ((unsigned int)(q8(c,s) & 255) << 16) | ((unsigned int)(q8(d,s) & 255) << 24);
}
__device__ __forceinline__ s8 qw(float w) {
  int q = __float2int_rn(w * 2032.0f);
  return (s8)max(-127, min(127, q));
}

// i8 MFMA via inline asm (A,B = 4 VGPRs = 16 i8 each; C/D = 4 VGPRs i32)
__device__ __forceinline__ i32x4 mfma_i8(i32x4 a, i32x4 b, i32x4 acc) {
  asm volatile("v_mfma_i32_16x16x64_i8 %0, %1, %2, %0" : "+v"(acc) : "v"(a), "v"(b));
  return acc;
}
// VGPR-tied wait so the compiler can't hoist acc reads above the MFMA pipeline drain
__device__ __forceinline__ i32x4 accfence(i32x4 acc) {
  asm volatile("s_nop 7\n\ts_nop 7" : "+v"(acc));
  return acc;
}

// ---------------- weight repack: f32 -> i8 MFMA A-fragments (runs every call) ----------------
__global__ void egbrnn_prep(
    const float* __restrict__ Wm0, const float* __restrict__ Wm1,
    const float* __restrict__ Wf10, const float* __restrict__ Wf11,
    const float* __restrict__ Wf20, const float* __restrict__ Wf21,
    const float* __restrict__ Wh0, const float* __restrict__ Wh1,
    const float* __restrict__ bm0, const float* __restrict__ bm1,
    const float* __restrict__ bf10, const float* __restrict__ bf11,
    const float* __restrict__ bf20, const float* __restrict__ bf21,
    const float* __restrict__ bh0, const float* __restrict__ bh1,
    u8* __restrict__ ws)
{
  int idx = blockIdx.x * 256 + threadIdx.x;
  // ---- PK1: Wm0, K = [c 0-255 | sn 256-259 | pad] ----
  if (idx < 81920) {
    int tile = idx >> 10, r = idx & 1023;
    int lane = r >> 4, j = r & 15;
    int ft = tile / 5, kt = tile % 5;
    int m = (ft << 4) + (lane & 15);
    int k = kt * 64 + ((lane >> 4) << 4) + j;
    float w = (k < 260) ? Wm0[k * 256 + m] : 0.f;
    ((s8*)ws)[idx] = qw(w);
    return;
  }
  idx -= 81920;
  // ---- PK2: [Wf10|Wf20|Wh0], K = [cu 0-255 | sn 256-259, meas 260-261 | pad] ----
  if (idx < 245760) {
    int tile = idx >> 10, r = idx & 1023;
    int lane = r >> 4, j = r & 15;
    int ft = tile / 5, kt = tile % 5;
    int F = (ft << 4) + (lane & 15);
    int k = kt * 64 + ((lane >> 4) << 4) + j;
    int sel = F >> 8, col = F & 255;
    float w = 0.f;
    if (sel == 0)      { if (k < 260) w = Wf10[k * 256 + col]; }
    else if (sel == 1) { if (k < 260) w = Wf20[k * 256 + col]; }
    else               { if (k < 262) w = Wh0 [k * 256 + col]; }
    ((s8*)ws)[81920 + idx] = qw(w);
    return;
  }
  idx -= 245760;
  // ---- PK3: Wm1; tile4 rows: kk0,1 -> meas rows 256,257; kk2-5 -> supd rows 258-261 ----
  if (idx < 81920) {
    int tile = idx >> 10, r = idx & 1023;
    int lane = r >> 4, j = r & 15;
    int ft = tile / 5, kt = tile % 5;
    int m = (ft << 4) + (lane & 15);
    int row = -1;
    if (kt < 4) row = kt * 64 + ((lane >> 4) << 4) + j;
    else {
      int kk = ((lane >> 4) << 4) + j;
      if (kk < 2) row = 256 + kk;
      else if (kk < 6) row = 258 + (kk - 2);
    }
    float w = (row >= 0) ? Wm1[row * 256 + m] : 0.f;
    ((s8*)ws)[327680 + idx] = qw(w);
    return;
  }
  idx -= 81920;
  // ---- biases (fp32) ----
  if (idx < 1288) {
    float* BIAS = (float*)(ws + 409600);
    float h;
    if (idx < 256) h = bm0[idx];
    else if (idx < 1024) {
      int f = idx - 256;
      h = (f < 256) ? bf10[f] : (f < 512 ? bf20[f - 256] : bh0[f - 512]);
    } else if (idx < 1280) h = bm1[idx - 1024];
    else {
      int i2 = idx - 1280;
      h = (i2 < 2) ? bf11[i2] : (i2 < 6 ? bf21[i2 - 2] : bh1[i2 - 6]);
    }
    BIAS[idx] = h;
    return;
  }
  idx -= 1288;
  // ---- head weights [o][k], bf16 ----
  if (idx < 2048) {
    int o = idx >> 8, k = idx & 255;
    float v;
    if (o < 2)      v = Wf11[k * 2 + o];
    else if (o < 6) v = Wf21[k * 4 + (o - 2)];
    else            v = Wh1[k * 2 + (o - 6)];
    ((u16*)(ws + 414752))[idx] = f2bf(v);
  }
}

// ---------------- main: 128 blocks x 1024 threads (16 waves), 16 batch rows per block ----------------
// Stage1 + stage3 weights register-resident (10 i8 frags/wave = 40 VGPR); only PK2 streams
// from L2 (240 KB/step vs 720 KB bf16 in R8).
__global__ __launch_bounds__(1024, 4) void egbrnn_main(
    const float* __restrict__ x, const float* __restrict__ target,
    const float* __restrict__ c0, const u8* __restrict__ wsp,
    float* __restrict__ out)
{
  // Activations in i8 MFMA B-fragment order: elem (k,n) at tile(k>>6)*1024 + ((k>>4)&3)*256 + n*16 + (k&15)
  __shared__ __align__(16) u8  ACT1[5 * 1024];   // tiles0-3: c/c_new; tile4: sn@kk0-3
  __shared__ __align__(16) u8  ACT2[6 * 1024];   // tiles0-3: cu; tile4a@4096: sn@0-3,meas@4,5; tile4b@5120: meas@0,1,supd@2-5
  __shared__ __align__(16) u16 S2O[16 * S2STR];  // [b][f] bf16: t1|t2|th
  __shared__ __align__(16) u16 HWs[2048];        // head weights [o][k]
  __shared__ __align__(16) float SM[128];        // [b][o]: d0 d1 pv0..3 hv0 hv1

  const u8* PK2 = wsp + 81920;
  const float* BIAS = (const float*)(wsp + 409600);
  const float* B1 = BIAS;
  const float* B2 = BIAS + 256;
  const float* B3 = BIAS + 1024;
  const float* BS = BIAS + 1280;

  const float SA = 0.0625f / 16129.0f;   // cu/c region rescale
  const float SB = 0.5f / 16129.0f;      // sn/meas/supd region rescale
  const float SC_SN = 127.0f / 480.0f;   // raw value -> /60 -> x127/8

  const int tid = threadIdx.x;
  const int wave = tid >> 6;     // 0..15
  const int lane = tid & 63;
  const int nidx = lane & 15;
  const int q = lane >> 4;
  const int boff = (q << 8) + (nidx << 4);   // B-frag lane byte offset within a 1 KB tile
  const int b0 = blockIdx.x << 4;

  // ---- register-resident stage1/stage3 weight fragments ----
  i32x4 rf1[5], rf3[5];
#pragma unroll
  for (int kt = 0; kt < 5; ++kt) {
    rf1[kt] = *(const i32x4*)(wsp + (((wave * 5 + kt)) << 10) + (lane << 4));
    rf3[kt] = *(const i32x4*)(wsp + 327680 + (((wave * 5 + kt)) << 10) + (lane << 4));
  }

  // head weights -> LDS
  for (int i = tid; i < 2048; i += 1024) HWs[i] = ((const u16*)(wsp + 414752))[i];

  // c0 -> ACT1 tiles0-3 (i8, scale 127); thread i writes one u32 (4 consecutive k, one b)
  {
    int p = tid << 2;
    int tile = p >> 10, r = p & 1023;
    int b = (r >> 4) & 15;
    int kg = tile * 64 + ((r >> 8) << 4) + (r & 15);
    float4 cv = *(const float4*)(c0 + (((size_t)(b0 + b)) << 8) + kg);
    *(unsigned int*)(ACT1 + p) = pack4q(cv.x, cv.y, cv.z, cv.w, 127.0f);
  }

  float s0v = 0.f, s1v = 0.f, s2v = 0.f, s3v = 0.f;
  float P[16];
#pragma unroll
  for (int i = 0; i < 16; ++i) P[i] = 0.f;
  if (tid < 16) {
    float4 tg = *(const float4*)(target + (((size_t)(b0 + tid)) << 9));
    s0v = tg.x; s1v = tg.y; s2v = tg.z; s3v = tg.w;
    P[0] = P[5] = P[10] = P[15] = 1.f;
    unsigned int snp = pack4q(s0v, s1v, s2v, s3v, SC_SN);
    *(unsigned int*)(ACT1 + 4096 + (tid << 4)) = snp;
    *(unsigned int*)(ACT2 + 4096 + (tid << 4)) = snp;
  }
  __syncthreads();

  // head assignment: 128 (o,b) pairs x 4 partial lanes (tid < 512)
  const int hpair = tid >> 2, hpart = tid & 3;
  const int hb = hpair & 15, ho = hpair >> 4;
  const int hcolBase = (ho < 2) ? 0 : ((ho < 6) ? 256 : 512);

  const i32x4 zero4 = {0, 0, 0, 0};

  for (int t = 0; t < T_STEPS; ++t) {
    // meas_t -> ACT2 tile4a bytes 4,5 (i8)
    if (tid < 16) {
      float2 mm = *(const float2*)(x + (((size_t)(b0 + tid)) << 8) + (t << 1));
      int qm0 = q8(mm.x, SC_SN), qm1 = q8(mm.y, SC_SN);
      *(u16*)(ACT2 + 4096 + (tid << 4) + 4) = (u16)((qm0 & 255) | ((qm1 & 255) << 8));
    }
    // ---- stage1: cu = tanh(Wm0 . [c, sn]); weights in registers ----
    {
      i32x4 aA = zero4, aB = zero4;
#pragma unroll
      for (int kt = 0; kt < 4; ++kt) {
        i32x4 bfr = *(const i32x4*)(ACT1 + (kt << 10) + boff);
        aA = mfma_i8(rf1[kt], bfr, aA);
      }
      {
        i32x4 bfr = *(const i32x4*)(ACT1 + 4096 + boff);
        aB = mfma_i8(rf1[4], bfr, aB);
      }
      aA = accfence(aA); aB = accfence(aB);
      const int f0 = (wave << 4) + (q << 2);
      const float4 bs = *(const float4*)(B1 + f0);
      float v0 = tanh_fast(clampf((float)aA[0] * SA + (float)aB[0] * SB + bs.x, -30.f, 30.f));
      float v1 = tanh_fast(clampf((float)aA[1] * SA + (float)aB[1] * SB + bs.y, -30.f, 30.f));
      float v2 = tanh_fast(clampf((float)aA[2] * SA + (float)aB[2] * SB + bs.z, -30.f, 30.f));
      float v3 = tanh_fast(clampf((float)aA[3] * SA + (float)aB[3] * SB + bs.w, -30.f, 30.f));
      const int kk = f0 & 63;
      *(unsigned int*)(ACT2 + ((f0 >> 6) << 10) + (((f0 >> 4) & 3) << 8) + (nidx << 4) + (kk & 15)) =
          pack4q(v0, v1, v2, v3, 127.0f);
    }
    __syncthreads();
    // ---- stage2: t1|t2|th; PK2 streams from L2 (15 frags/wave) ----
    {
      i32x4 cA[3], cB[3];
#pragma unroll
      for (int i = 0; i < 3; ++i) { cA[i] = zero4; cB[i] = zero4; }
#pragma unroll
      for (int kt = 0; kt < 5; ++kt) {
        i32x4 bfr = *(const i32x4*)(ACT2 + (kt << 10) + boff);   // kt4 -> tile4a @4096
#pragma unroll
        for (int i = 0; i < 3; ++i) {
          i32x4 af = *(const i32x4*)(PK2 + (((wave + 16 * i) * 5 + kt) << 10) + (lane << 4));
          if (kt < 4) cA[i] = mfma_i8(af, bfr, cA[i]);
          else        cB[i] = mfma_i8(af, bfr, cB[i]);
        }
      }
#pragma unroll
      for (int i = 0; i < 3; ++i) {
        cA[i] = accfence(cA[i]); cB[i] = accfence(cB[i]);
        const int ft = wave + 16 * i;
        const int f0 = (ft << 4) + (q << 2);
        const float4 bs = *(const float4*)(B2 + f0);
        float v0 = tanh_fast(clampf((float)cA[i][0] * SA + (float)cB[i][0] * SB + bs.x, -30.f, 30.f));
        float v1 = tanh_fast(clampf((float)cA[i][1] * SA + (float)cB[i][1] * SB + bs.y, -30.f, 30.f));
        float v2 = tanh_fast(clampf((float)cA[i][2] * SA + (float)cB[i][2] * SB + bs.z, -30.f, 30.f));
        float v3 = tanh_fast(clampf((float)cA[i][3] * SA + (float)cB[i][3] * SB + bs.w, -30.f, 30.f));
        uint2 pv; pv.x = pack2(v0, v1); pv.y = pack2(v2, v3);
        *(uint2*)(S2O + nidx * S2STR + f0) = pv;
      }
    }
    __syncthreads();
    // ---- small heads: 128 (o,b) bf16 dots of length 256; 4 partial lanes each ----
    if (tid < 512) {
      const u16* ap = S2O + hb * S2STR + hcolBase + (hpart << 6);
      const u16* wp = HWs + (ho << 8) + (hpart << 6);
      float p = 0.f;
#pragma unroll
      for (int i = 0; i < 8; ++i) {
        bf16x8 av = *(const bf16x8*)(ap + (i << 3));
        bf16x8 wv = *(const bf16x8*)(wp + (i << 3));
#pragma unroll
        for (int j = 0; j < 8; ++j) p += (float)av[j] * (float)wv[j];
      }
      p += __shfl_xor(p, 1);
      p += __shfl_xor(p, 2);
      if (hpart == 0) SM[hb * 8 + ho] = clampf(p + BS[ho], -64.f, 64.f);
    }
    __syncthreads();
    // ---- Kalman update (lane b owns batch row b; s,P fp32 registers) ----
    if (tid < 16) {
      const float* sm = SM + tid * 8;
      float d0 = sm[0], d1 = sm[1];
      float pv[4] = { sm[2], sm[3], sm[4], sm[5] };
      float hv0 = sm[6], hv1 = sm[7];
      float2 mm = *(const float2*)(x + (((size_t)(b0 + tid)) << 8) + (t << 1));
      float m0 = mm.x, m1 = mm.y;
      float sp[4];
      sp[0] = s0v + s2v + 0.5f * d0;
      sp[1] = s1v + s3v + 0.5f * d1;
      sp[2] = s2v + d0;
      sp[3] = s3v + d1;
      float FP[16], Pp[16];
#pragma unroll
      for (int j = 0; j < 4; ++j) {
        FP[0 * 4 + j] = P[0 * 4 + j] + P[2 * 4 + j];
        FP[1 * 4 + j] = P[1 * 4 + j] + P[3 * 4 + j];
        FP[2 * 4 + j] = P[2 * 4 + j];
        FP[3 * 4 + j] = P[3 * 4 + j];
      }
#pragma unroll
      for (int i = 0; i < 4; ++i) {
        Pp[i * 4 + 0] = FP[i * 4 + 0] + FP[i * 4 + 2];
        Pp[i * 4 + 1] = FP[i * 4 + 1] + FP[i * 4 + 3];
        Pp[i * 4 + 2] = FP[i * 4 + 2];
        Pp[i * 4 + 3] = FP[i * 4 + 3];
      }
#pragma unroll
      for (int i = 0; i < 4; ++i)
#pragma unroll
        for (int j = 0; j < 4; ++j) Pp[i * 4 + j] += pv[i] * pv[j];
#pragma unroll
      for (int i = 0; i < 4; ++i) Pp[i * 4 + i] += 0.01f;
      float in0 = m0 - sp[0], in1 = m1 - sp[1];
      float S00 = Pp[0] + hv0 * hv0 + 1.0f;
      float S01 = Pp[1] + hv0 * hv1;
      float S10 = Pp[4] + hv1 * hv0;
      float S11 = Pp[5] + hv1 * hv1 + 1.0f;
      float det = S00 * S11 - S01 * S10;
      if (!(fabsf(det) > 1e-8f)) det = 1e-8f;
      float idet = 1.0f / det;
      float i00 =  S11 * idet, i01 = -S01 * idet, i10 = -S10 * idet, i11 = S00 * idet;
      float K[8], KS[8], su[4];
#pragma unroll
      for (int i = 0; i < 4; ++i) {
        K[i * 2 + 0] = Pp[i * 4 + 0] * i00 + Pp[i * 4 + 1] * i10;
        K[i * 2 + 1] = Pp[i * 4 + 0] * i01 + Pp[i * 4 + 1] * i11;
      }
#pragma unroll
      for (int i = 0; i < 4; ++i)
        su[i] = clampf(sp[i] + K[i * 2 + 0] * in0 + K[i * 2 + 1] * in1, -131072.f, 131072.f);
#pragma unroll
      for (int i = 0; i < 4; ++i) {
        KS[i * 2 + 0] = K[i * 2 + 0] * S00 + K[i * 2 + 1] * S10;
        KS[i * 2 + 1] = K[i * 2 + 0] * S01 + K[i * 2 + 1] * S11;
      }
#pragma unroll
      for (int i = 0; i < 4; ++i)
#pragma unroll
        for (int j = 0; j < 4; ++j)
          P[i * 4 + j] = clampf(
              Pp[i * 4 + j] - (KS[i * 2 + 0] * K[j * 2 + 0] + KS[i * 2 + 1] * K[j * 2 + 1]),
              -131072.f, 131072.f);
      s0v = su[0]; s1v = su[1]; s2v = su[2]; s3v = su[3];
      // output s_upd (f32)
      float4 ov; ov.x = su[0]; ov.y = su[1]; ov.z = su[2]; ov.w = su[3];
      *(float4*)(out + (((size_t)(b0 + tid)) << 9) + (t << 2)) = ov;
      // sn_{t+1} (ACT1 tile4, ACT2 tile4a) + tile4b [meas0,meas1,supd0..3] (i8)
      unsigned int snp = pack4q(su[0], su[1], su[2], su[3], SC_SN);
      *(unsigned int*)(ACT1 + 4096 + (tid << 4)) = snp;
      *(unsigned int*)(ACT2 + 4096 + (tid << 4)) = snp;
      int qm0 = q8(m0, SC_SN), qm1 = q8(m1, SC_SN);
      *(unsigned int*)(ACT2 + 5120 + (tid << 4)) =
          (unsigned int)(qm0 & 255) | ((unsigned int)(qm1 & 255) << 8) |
          ((snp & 255) << 16) | (((snp >> 8) & 255) << 24);
      *(u16*)(ACT2 + 5120 + (tid << 4) + 4) = (u16)((snp >> 16) & 0xffffu);
    }
    __syncthreads();
    // ---- stage3: c_new = tanh(Wm1 . [cu, meas, supd]); weights in registers ----
    {
      i32x4 aA = zero4, aB = zero4;
#pragma unroll
      for (int kt = 0; kt < 4; ++kt) {
        i32x4 bfr = *(const i32x4*)(ACT2 + (kt << 10) + boff);
        aA = mfma_i8(rf3[kt], bfr, aA);
      }
      {
        i32x4 bfr = *(const i32x4*)(ACT2 + 5120 + boff);   // tile4b
        aB = mfma_i8(rf3[4], bfr, aB);
      }
      aA = accfence(aA); aB = accfence(aB);
      const int f0 = (wave << 4) + (q << 2);
      const float4 bs = *(const float4*)(B3 + f0);
      float v0 = tanh_fast(clampf((float)aA[0] * SA + (float)aB[0] * SB + bs.x, -30.f, 30.f));
      float v1 = tanh_fast(clampf((float)aA[1] * SA + (float)aB[1] * SB + bs.y, -30.f, 30.f));
      float v2 = tanh_fast(clampf((float)aA[2] * SA + (float)aB[2] * SB + bs.z, -30.f, 30.f));
      float v3 = tanh_fast(clampf((float)aA[3] * SA + (float)aB[3] * SB + bs.w, -30.f, 30.f));
      const int kk = f0 & 63;
      *(unsigned int*)(ACT1 + ((f0 >> 6) << 10) + (((f0 >> 4) & 3) << 8) + (nidx << 4) + (kk & 15)) =
          pack4q(v0, v1, v2, v3, 127.0f);
    }
    __syncthreads();
  }
}

extern "C" void kernel_launch(void* const* d_in, const int* in_sizes, int n_in,
                              void* d_out, int out_size, void* d_ws, size_t ws_size,
                              hipStream_t stream) {
  const float* x    = (const float*)d_in[0];
  const float* tgt  = (const float*)d_in[1];
  const float* c0   = (const float*)d_in[2];
  const float* Wm0  = (const float*)d_in[3];
  const float* bm0  = (const float*)d_in[4];
  const float* Wm1  = (const float*)d_in[5];
  const float* bm1  = (const float*)d_in[6];
  const float* Wf10 = (const float*)d_in[7];
  const float* bf10 = (const float*)d_in[8];
  const float* Wf11 = (const float*)d_in[9];
  const float* bf11 = (const float*)d_in[10];
  const float* Wf20 = (const float*)d_in[11];
  const float* bf20 = (const float*)d_in[12];
  const float* Wf21 = (const float*)d_in[13];
  const float* bf21 = (const float*)d_in[14];
  const float* Wh0  = (const float*)d_in[15];
  const float* bh0  = (const float*)d_in[16];
  const float* Wh1  = (const float*)d_in[17];
  const float* bh1  = (const float*)d_in[18];
  u8* ws     = (u8*)d_ws;
  float* out = (float*)d_out;

  // total prep threads: 81920+245760+81920+1288+2048 = 412936
  egbrnn_prep<<<dim3(1614), dim3(256), 0, stream>>>(
      Wm0, Wm1, Wf10, Wf11, Wf20, Wf21, Wh0, Wh1,
      bm0, bm1, bf10, bf11, bf20, bf21, bh0, bh1, ws);
  egbrnn_main<<<dim3(128), dim3(1024), 0, stream>>>(x, tgt, c0, ws, out);
}

// Round 10
// 928.759 us; speedup vs baseline: 1.3450x; 1.3450x over previous
//
#include <hip/hip_runtime.h>

typedef unsigned short u16;
typedef unsigned char  u8;
typedef signed char    s8;
typedef __bf16 bf16x8 __attribute__((ext_vector_type(8)));
typedef int    i32x4  __attribute__((ext_vector_type(4)));

#define T_STEPS 128
#define S2STR   776    // stage2 output row stride (u16): 768 + 8 pad

// ---- ws BYTE layout ----
// PK1  @      0 : 16 ft x 5 kt x 1024 =  81920  (Wm0 -> i8 A-frags, 16x16x64)
// PK2  @  81920 : 48 x 5 x 1024      = 245760  (Wf10|Wf20|Wh0)
// PK3  @ 327680 : 16 x 5 x 1024      =  81920  (Wm1, rows permuted)
// BIAS @ 409600 : 1288 f32 (B1[256] B2[768] B3[256] BS[8])
// HW   @ 414752 : 2048 bf16 (head weights [o][k])
//
// Quant: weights w_q = rne(w * 2032); |w|<=1/sqrt(260)<0.0625 -> |w_q|<=127.
// Activations: cu/c region scale 127 (|v|<1); sn/meas/supd region scale 127/480.
// Epilogue: pre = accA*SA + accB*SB + bias; SA = 0.0625/127^2, SB = 0.5/127^2.

__device__ __forceinline__ float bf2f(u16 h) {
  union { unsigned int u; float f; } v; v.u = ((unsigned int)h) << 16; return v.f;
}
__device__ __forceinline__ u16 f2bf(float f) {
  union { float f; unsigned int u; } v; v.f = f;
  unsigned int u = v.u;
  return (u16)((u + 0x7fffu + ((u >> 16) & 1u)) >> 16);
}
__device__ __forceinline__ unsigned int pack2(float a, float b) {
  return (unsigned int)f2bf(a) | ((unsigned int)f2bf(b) << 16);
}
__device__ __forceinline__ float clampf(float x, float lo, float hi) {
  return fmaxf(lo, fminf(x, hi));   // NaN-absorbing insurance
}
__device__ __forceinline__ float tanh_fast(float x) {
  float e = __expf(2.0f * x);
  return 1.0f - 2.0f * __builtin_amdgcn_rcpf(e + 1.0f);
}
__device__ __forceinline__ int q8(float v, float s) {
  int q = __float2int_rn(v * s);
  return max(-127, min(127, q));
}
__device__ __forceinline__ unsigned int pack4q(float a, float b, float c, float d, float s) {
  return (unsigned int)(q8(a,s) & 255) | ((unsigned int)(q8(b,s) & 255) << 8) |
         ((unsigned int)(q8(c,s) & 255) << 16) | ((unsigned int)(q8(d,s) & 255) << 24);
}
__device__ __forceinline__ s8 qw(float w) {
  int q = __float2int_rn(w * 2032.0f);
  return (s8)max(-127, min(127, q));
}

// i8 MFMA via inline asm (A,B = 4 VGPRs = 16 i8 each; C/D = 4 VGPRs i32)
__device__ __forceinline__ i32x4 mfma_i8(i32x4 a, i32x4 b, i32x4 acc) {
  asm volatile("v_mfma_i32_16x16x64_i8 %0, %1, %2, %0" : "+v"(acc) : "v"(a), "v"(b));
  return acc;
}
// VGPR-tied wait so the compiler can't hoist acc reads above the MFMA pipeline drain
__device__ __forceinline__ i32x4 accfence(i32x4 acc) {
  asm volatile("s_nop 7\n\ts_nop 7" : "+v"(acc));
  return acc;
}

// ---------------- weight repack: f32 -> i8 MFMA A-fragments (runs every call) ----------------
__global__ void egbrnn_prep(
    const float* __restrict__ Wm0, const float* __restrict__ Wm1,
    const float* __restrict__ Wf10, const float* __restrict__ Wf11,
    const float* __restrict__ Wf20, const float* __restrict__ Wf21,
    const float* __restrict__ Wh0, const float* __restrict__ Wh1,
    const float* __restrict__ bm0, const float* __restrict__ bm1,
    const float* __restrict__ bf10, const float* __restrict__ bf11,
    const float* __restrict__ bf20, const float* __restrict__ bf21,
    const float* __restrict__ bh0, const float* __restrict__ bh1,
    u8* __restrict__ ws)
{
  int idx = blockIdx.x * 256 + threadIdx.x;
  // ---- PK1: Wm0, K = [c 0-255 | sn 256-259 | pad] ----
  if (idx < 81920) {
    int tile = idx >> 10, r = idx & 1023;
    int lane = r >> 4, j = r & 15;
    int ft = tile / 5, kt = tile % 5;
    int m = (ft << 4) + (lane & 15);
    int k = kt * 64 + ((lane >> 4) << 4) + j;
    float w = (k < 260) ? Wm0[k * 256 + m] : 0.f;
    ((s8*)ws)[idx] = qw(w);
    return;
  }
  idx -= 81920;
  // ---- PK2: [Wf10|Wf20|Wh0], K = [cu 0-255 | sn 256-259, meas 260-261 | pad] ----
  if (idx < 245760) {
    int tile = idx >> 10, r = idx & 1023;
    int lane = r >> 4, j = r & 15;
    int ft = tile / 5, kt = tile % 5;
    int F = (ft << 4) + (lane & 15);
    int k = kt * 64 + ((lane >> 4) << 4) + j;
    int sel = F >> 8, col = F & 255;
    float w = 0.f;
    if (sel == 0)      { if (k < 260) w = Wf10[k * 256 + col]; }
    else if (sel == 1) { if (k < 260) w = Wf20[k * 256 + col]; }
    else               { if (k < 262) w = Wh0 [k * 256 + col]; }
    ((s8*)ws)[81920 + idx] = qw(w);
    return;
  }
  idx -= 245760;
  // ---- PK3: Wm1; tile4 rows: kk0,1 -> meas rows 256,257; kk2-5 -> supd rows 258-261 ----
  if (idx < 81920) {
    int tile = idx >> 10, r = idx & 1023;
    int lane = r >> 4, j = r & 15;
    int ft = tile / 5, kt = tile % 5;
    int m = (ft << 4) + (lane & 15);
    int row = -1;
    if (kt < 4) row = kt * 64 + ((lane >> 4) << 4) + j;
    else {
      int kk = ((lane >> 4) << 4) + j;
      if (kk < 2) row = 256 + kk;
      else if (kk < 6) row = 258 + (kk - 2);
    }
    float w = (row >= 0) ? Wm1[row * 256 + m] : 0.f;
    ((s8*)ws)[327680 + idx] = qw(w);
    return;
  }
  idx -= 81920;
  // ---- biases (fp32) ----
  if (idx < 1288) {
    float* BIAS = (float*)(ws + 409600);
    float h;
    if (idx < 256) h = bm0[idx];
    else if (idx < 1024) {
      int f = idx - 256;
      h = (f < 256) ? bf10[f] : (f < 512 ? bf20[f - 256] : bh0[f - 512]);
    } else if (idx < 1280) h = bm1[idx - 1024];
    else {
      int i2 = idx - 1280;
      h = (i2 < 2) ? bf11[i2] : (i2 < 6 ? bf21[i2 - 2] : bh1[i2 - 6]);
    }
    BIAS[idx] = h;
    return;
  }
  idx -= 1288;
  // ---- head weights [o][k], bf16 ----
  if (idx < 2048) {
    int o = idx >> 8, k = idx & 255;
    float v;
    if (o < 2)      v = Wf11[k * 2 + o];
    else if (o < 6) v = Wf21[k * 4 + (o - 2)];
    else            v = Wh1[k * 2 + (o - 6)];
    ((u16*)(ws + 414752))[idx] = f2bf(v);
  }
}

// ---------------- main: 128 blocks x 1024 threads (16 waves), 16 batch rows per block ----------------
// All weights stream from L2 (400 KB/step i8 vs 720 KB bf16 in R8). No register pinning —
// the compiler enforces 64 VGPRs at this block size and pinning spills (R9: 33 MB scratch).
__global__ __launch_bounds__(1024, 4) void egbrnn_main(
    const float* __restrict__ x, const float* __restrict__ target,
    const float* __restrict__ c0, const u8* __restrict__ wsp,
    float* __restrict__ out)
{
  // Activations in i8 MFMA B-fragment order: elem (k,n) at tile(k>>6)*1024 + ((k>>4)&3)*256 + n*16 + (k&15)
  __shared__ __align__(16) u8  ACT1[5 * 1024];   // tiles0-3: c/c_new; tile4: sn@kk0-3
  __shared__ __align__(16) u8  ACT2[6 * 1024];   // tiles0-3: cu; tile4a@4096: sn@0-3,meas@4,5; tile4b@5120: meas@0,1,supd@2-5
  __shared__ __align__(16) u16 S2O[16 * S2STR];  // [b][f] bf16: t1|t2|th
  __shared__ __align__(16) u16 HWs[2048];        // head weights [o][k]
  __shared__ __align__(16) float SM[128];        // [b][o]: d0 d1 pv0..3 hv0 hv1

  const float* BIAS = (const float*)(wsp + 409600);
  const float* B1 = BIAS;
  const float* B2 = BIAS + 256;
  const float* B3 = BIAS + 1024;
  const float* BS = BIAS + 1280;

  const float SA = 0.0625f / 16129.0f;   // cu/c region rescale
  const float SB = 0.5f / 16129.0f;      // sn/meas/supd region rescale
  const float SC_SN = 127.0f / 480.0f;   // raw value -> /60 -> x127/8

  const int tid = threadIdx.x;
  const int wave = tid >> 6;     // 0..15
  const int lane = tid & 63;
  const int nidx = lane & 15;
  const int q = lane >> 4;
  const int boff = (q << 8) + (nidx << 4);   // B-frag lane byte offset within a 1 KB tile
  const int loff = lane << 4;                // A-frag lane byte offset
  const int b0 = blockIdx.x << 4;

  // wave-uniform A-frag base pointers (readfirstlane -> SGPR; loads become base+voffset+imm)
  const int wvu = __builtin_amdgcn_readfirstlane(wave);
  const u8* pk1w  = wsp + wvu * 5120;
  const u8* pk2w0 = wsp + 81920 + wvu * 5120;
  const u8* pk2w1 = wsp + 81920 + (wvu + 16) * 5120;
  const u8* pk2w2 = wsp + 81920 + (wvu + 32) * 5120;
  const u8* pk3w  = wsp + 327680 + wvu * 5120;

  // head weights -> LDS
  for (int i = tid; i < 2048; i += 1024) HWs[i] = ((const u16*)(wsp + 414752))[i];

  // c0 -> ACT1 tiles0-3 (i8, scale 127); thread i writes one u32 (4 consecutive k, one b)
  {
    int p = tid << 2;
    int tile = p >> 10, r = p & 1023;
    int b = (r >> 4) & 15;
    int kg = tile * 64 + ((r >> 8) << 4) + (r & 15);
    float4 cv = *(const float4*)(c0 + (((size_t)(b0 + b)) << 8) + kg);
    *(unsigned int*)(ACT1 + p) = pack4q(cv.x, cv.y, cv.z, cv.w, 127.0f);
  }

  float s0v = 0.f, s1v = 0.f, s2v = 0.f, s3v = 0.f;
  float P[16];
#pragma unroll
  for (int i = 0; i < 16; ++i) P[i] = 0.f;
  if (tid < 16) {
    float4 tg = *(const float4*)(target + (((size_t)(b0 + tid)) << 9));
    s0v = tg.x; s1v = tg.y; s2v = tg.z; s3v = tg.w;
    P[0] = P[5] = P[10] = P[15] = 1.f;
    unsigned int snp = pack4q(s0v, s1v, s2v, s3v, SC_SN);
    *(unsigned int*)(ACT1 + 4096 + (tid << 4)) = snp;
    *(unsigned int*)(ACT2 + 4096 + (tid << 4)) = snp;
  }
  __syncthreads();

  // head assignment: 128 (o,b) pairs x 4 partial lanes (tid < 512)
  const int hpair = tid >> 2, hpart = tid & 3;
  const int hb = hpair & 15, ho = hpair >> 4;
  const int hcolBase = (ho < 2) ? 0 : ((ho < 6) ? 256 : 512);

  const i32x4 zero4 = {0, 0, 0, 0};

  for (int t = 0; t < T_STEPS; ++t) {
    // meas_t -> ACT2 tile4a bytes 4,5 (i8)
    if (tid < 16) {
      float2 mm = *(const float2*)(x + (((size_t)(b0 + tid)) << 8) + (t << 1));
      int qm0 = q8(mm.x, SC_SN), qm1 = q8(mm.y, SC_SN);
      *(u16*)(ACT2 + 4096 + (tid << 4) + 4) = (u16)((qm0 & 255) | ((qm1 & 255) << 8));
    }
    // ---- stage1: cu = tanh(Wm0 . [c, sn]) ----
    {
      i32x4 aA = zero4, aB = zero4;
#pragma unroll
      for (int kt = 0; kt < 4; ++kt) {
        i32x4 bfr = *(const i32x4*)(ACT1 + (kt << 10) + boff);
        i32x4 af  = *(const i32x4*)(pk1w + (kt << 10) + loff);
        aA = mfma_i8(af, bfr, aA);
      }
      {
        i32x4 bfr = *(const i32x4*)(ACT1 + 4096 + boff);
        i32x4 af  = *(const i32x4*)(pk1w + 4096 + loff);
        aB = mfma_i8(af, bfr, aB);
      }
      aA = accfence(aA); aB = accfence(aB);
      const int f0 = (wave << 4) + (q << 2);
      const float4 bs = *(const float4*)(B1 + f0);
      float v0 = tanh_fast(clampf((float)aA[0] * SA + (float)aB[0] * SB + bs.x, -30.f, 30.f));
      float v1 = tanh_fast(clampf((float)aA[1] * SA + (float)aB[1] * SB + bs.y, -30.f, 30.f));
      float v2 = tanh_fast(clampf((float)aA[2] * SA + (float)aB[2] * SB + bs.z, -30.f, 30.f));
      float v3 = tanh_fast(clampf((float)aA[3] * SA + (float)aB[3] * SB + bs.w, -30.f, 30.f));
      const int kk = f0 & 63;
      *(unsigned int*)(ACT2 + ((f0 >> 6) << 10) + (((f0 >> 4) & 3) << 8) + (nidx << 4) + (kk & 15)) =
          pack4q(v0, v1, v2, v3, 127.0f);
    }
    __syncthreads();
    // ---- stage2: t1|t2|th; PK2 streams from L2 (15 frags/wave) ----
    {
      i32x4 cA[3], cB[3];
#pragma unroll
      for (int i = 0; i < 3; ++i) { cA[i] = zero4; cB[i] = zero4; }
#pragma unroll
      for (int kt = 0; kt < 5; ++kt) {
        i32x4 bfr = *(const i32x4*)(ACT2 + (kt << 10) + boff);   // kt4 -> tile4a @4096
        i32x4 af0 = *(const i32x4*)(pk2w0 + (kt << 10) + loff);
        i32x4 af1 = *(const i32x4*)(pk2w1 + (kt << 10) + loff);
        i32x4 af2 = *(const i32x4*)(pk2w2 + (kt << 10) + loff);
        if (kt < 4) {
          cA[0] = mfma_i8(af0, bfr, cA[0]);
          cA[1] = mfma_i8(af1, bfr, cA[1]);
          cA[2] = mfma_i8(af2, bfr, cA[2]);
        } else {
          cB[0] = mfma_i8(af0, bfr, cB[0]);
          cB[1] = mfma_i8(af1, bfr, cB[1]);
          cB[2] = mfma_i8(af2, bfr, cB[2]);
        }
      }
#pragma unroll
      for (int i = 0; i < 3; ++i) {
        cA[i] = accfence(cA[i]); cB[i] = accfence(cB[i]);
        const int ft = wave + 16 * i;
        const int f0 = (ft << 4) + (q << 2);
        const float4 bs = *(const float4*)(B2 + f0);
        float v0 = tanh_fast(clampf((float)cA[i][0] * SA + (float)cB[i][0] * SB + bs.x, -30.f, 30.f));
        float v1 = tanh_fast(clampf((float)cA[i][1] * SA + (float)cB[i][1] * SB + bs.y, -30.f, 30.f));
        float v2 = tanh_fast(clampf((float)cA[i][2] * SA + (float)cB[i][2] * SB + bs.z, -30.f, 30.f));
        float v3 = tanh_fast(clampf((float)cA[i][3] * SA + (float)cB[i][3] * SB + bs.w, -30.f, 30.f));
        uint2 pv; pv.x = pack2(v0, v1); pv.y = pack2(v2, v3);
        *(uint2*)(S2O + nidx * S2STR + f0) = pv;
      }
    }
    __syncthreads();
    // ---- small heads: 128 (o,b) bf16 dots of length 256; 4 partial lanes each ----
    if (tid < 512) {
      const u16* ap = S2O + hb * S2STR + hcolBase + (hpart << 6);
      const u16* wp = HWs + (ho << 8) + (hpart << 6);
      float p = 0.f;
#pragma unroll
      for (int i = 0; i < 8; ++i) {
        bf16x8 av = *(const bf16x8*)(ap + (i << 3));
        bf16x8 wv = *(const bf16x8*)(wp + (i << 3));
#pragma unroll
        for (int j = 0; j < 8; ++j) p += (float)av[j] * (float)wv[j];
      }
      p += __shfl_xor(p, 1);
      p += __shfl_xor(p, 2);
      if (hpart == 0) SM[hb * 8 + ho] = clampf(p + BS[ho], -64.f, 64.f);
    }
    __syncthreads();
    // ---- Kalman update (lane b owns batch row b; s,P fp32 registers) ----
    if (tid < 16) {
      const float* sm = SM + tid * 8;
      float d0 = sm[0], d1 = sm[1];
      float pv[4] = { sm[2], sm[3], sm[4], sm[5] };
      float hv0 = sm[6], hv1 = sm[7];
      float2 mm = *(const float2*)(x + (((size_t)(b0 + tid)) << 8) + (t << 1));
      float m0 = mm.x, m1 = mm.y;
      float sp[4];
      sp[0] = s0v + s2v + 0.5f * d0;
      sp[1] = s1v + s3v + 0.5f * d1;
      sp[2] = s2v + d0;
      sp[3] = s3v + d1;
      float FP[16], Pp[16];
#pragma unroll
      for (int j = 0; j < 4; ++j) {
        FP[0 * 4 + j] = P[0 * 4 + j] + P[2 * 4 + j];
        FP[1 * 4 + j] = P[1 * 4 + j] + P[3 * 4 + j];
        FP[2 * 4 + j] = P[2 * 4 + j];
        FP[3 * 4 + j] = P[3 * 4 + j];
      }
#pragma unroll
      for (int i = 0; i < 4; ++i) {
        Pp[i * 4 + 0] = FP[i * 4 + 0] + FP[i * 4 + 2];
        Pp[i * 4 + 1] = FP[i * 4 + 1] + FP[i * 4 + 3];
        Pp[i * 4 + 2] = FP[i * 4 + 2];
        Pp[i * 4 + 3] = FP[i * 4 + 3];
      }
#pragma unroll
      for (int i = 0; i < 4; ++i)
#pragma unroll
        for (int j = 0; j < 4; ++j) Pp[i * 4 + j] += pv[i] * pv[j];
#pragma unroll
      for (int i = 0; i < 4; ++i) Pp[i * 4 + i] += 0.01f;
      float in0 = m0 - sp[0], in1 = m1 - sp[1];
      float S00 = Pp[0] + hv0 * hv0 + 1.0f;
      float S01 = Pp[1] + hv0 * hv1;
      float S10 = Pp[4] + hv1 * hv0;
      float S11 = Pp[5] + hv1 * hv1 + 1.0f;
      float det = S00 * S11 - S01 * S10;
      if (!(fabsf(det) > 1e-8f)) det = 1e-8f;
      float idet = 1.0f / det;
      float i00 =  S11 * idet, i01 = -S01 * idet, i10 = -S10 * idet, i11 = S00 * idet;
      float K[8], KS[8], su[4];
#pragma unroll
      for (int i = 0; i < 4; ++i) {
        K[i * 2 + 0] = Pp[i * 4 + 0] * i00 + Pp[i * 4 + 1] * i10;
        K[i * 2 + 1] = Pp[i * 4 + 0] * i01 + Pp[i * 4 + 1] * i11;
      }
#pragma unroll
      for (int i = 0; i < 4; ++i)
        su[i] = clampf(sp[i] + K[i * 2 + 0] * in0 + K[i * 2 + 1] * in1, -131072.f, 131072.f);
#pragma unroll
      for (int i = 0; i < 4; ++i) {
        KS[i * 2 + 0] = K[i * 2 + 0] * S00 + K[i * 2 + 1] * S10;
        KS[i * 2 + 1] = K[i * 2 + 0] * S01 + K[i * 2 + 1] * S11;
      }
#pragma unroll
      for (int i = 0; i < 4; ++i)
#pragma unroll
        for (int j = 0; j < 4; ++j)
          P[i * 4 + j] = clampf(
              Pp[i * 4 + j] - (KS[i * 2 + 0] * K[j * 2 + 0] + KS[i * 2 + 1] * K[j * 2 + 1]),
              -131072.f, 131072.f);
      s0v = su[0]; s1v = su[1]; s2v = su[2]; s3v = su[3];
      // output s_upd (f32)
      float4 ov; ov.x = su[0]; ov.y = su[1]; ov.z = su[2]; ov.w = su[3];
      *(float4*)(out + (((size_t)(b0 + tid)) << 9) + (t << 2)) = ov;
      // sn_{t+1} (ACT1 tile4, ACT2 tile4a) + tile4b [meas0,meas1,supd0..3] (i8)
      unsigned int snp = pack4q(su[0], su[1], su[2], su[3], SC_SN);
      *(unsigned int*)(ACT1 + 4096 + (tid << 4)) = snp;
      *(unsigned int*)(ACT2 + 4096 + (tid << 4)) = snp;
      int qm0 = q8(m0, SC_SN), qm1 = q8(m1, SC_SN);
      *(unsigned int*)(ACT2 + 5120 + (tid << 4)) =
          (unsigned int)(qm0 & 255) | ((unsigned int)(qm1 & 255) << 8) |
          ((snp & 255) << 16) | (((snp >> 8) & 255) << 24);
      *(u16*)(ACT2 + 5120 + (tid << 4) + 4) = (u16)((snp >> 16) & 0xffffu);
    }
    __syncthreads();
    // ---- stage3: c_new = tanh(Wm1 . [cu, meas, supd]) ----
    {
      i32x4 aA = zero4, aB = zero4;
#pragma unroll
      for (int kt = 0; kt < 4; ++kt) {
        i32x4 bfr = *(const i32x4*)(ACT2 + (kt << 10) + boff);
        i32x4 af  = *(const i32x4*)(pk3w + (kt << 10) + loff);
        aA = mfma_i8(af, bfr, aA);
      }
      {
        i32x4 bfr = *(const i32x4*)(ACT2 + 5120 + boff);   // tile4b
        i32x4 af  = *(const i32x4*)(pk3w + 4096 + loff);
        aB = mfma_i8(af, bfr, aB);
      }
      aA = accfence(aA); aB = accfence(aB);
      const int f0 = (wave << 4) + (q << 2);
      const float4 bs = *(const float4*)(B3 + f0);
      float v0 = tanh_fast(clampf((float)aA[0] * SA + (float)aB[0] * SB + bs.x, -30.f, 30.f));
      float v1 = tanh_fast(clampf((float)aA[1] * SA + (float)aB[1] * SB + bs.y, -30.f, 30.f));
      float v2 = tanh_fast(clampf((float)aA[2] * SA + (float)aB[2] * SB + bs.z, -30.f, 30.f));
      float v3 = tanh_fast(clampf((float)aA[3] * SA + (float)aB[3] * SB + bs.w, -30.f, 30.f));
      const int kk = f0 & 63;
      *(unsigned int*)(ACT1 + ((f0 >> 6) << 10) + (((f0 >> 4) & 3) << 8) + (nidx << 4) + (kk & 15)) =
          pack4q(v0, v1, v2, v3, 127.0f);
    }
    __syncthreads();
  }
}

extern "C" void kernel_launch(void* const* d_in, const int* in_sizes, int n_in,
                              void* d_out, int out_size, void* d_ws, size_t ws_size,
                              hipStream_t stream) {
  const float* x    = (const float*)d_in[0];
  const float* tgt  = (const float*)d_in[1];
  const float* c0   = (const float*)d_in[2];
  const float* Wm0  = (const float*)d_in[3];
  const float* bm0  = (const float*)d_in[4];
  const float* Wm1  = (const float*)d_in[5];
  const float* bm1  = (const float*)d_in[6];
  const float* Wf10 = (const float*)d_in[7];
  const float* bf10 = (const float*)d_in[8];
  const float* Wf11 = (const float*)d_in[9];
  const float* bf11 = (const float*)d_in[10];
  const float* Wf20 = (const float*)d_in[11];
  const float* bf20 = (const float*)d_in[12];
  const float* Wf21 = (const float*)d_in[13];
  const float* bf21 = (const float*)d_in[14];
  const float* Wh0  = (const float*)d_in[15];
  const float* bh0  = (const float*)d_in[16];
  const float* Wh1  = (const float*)d_in[17];
  const float* bh1  = (const float*)d_in[18];
  u8* ws     = (u8*)d_ws;
  float* out = (float*)d_out;

  // total prep threads: 81920+245760+81920+1288+2048 = 412936
  egbrnn_prep<<<dim3(1614), dim3(256), 0, stream>>>(
      Wm0, Wm1, Wf10, Wf11, Wf20, Wf21, Wh0, Wh1,
      bm0, bm1, bf10, bf11, bf20, bf21, bh0, bh1, ws);
  egbrnn_main<<<dim3(128), dim3(1024), 0, stream>>>(x, tgt, c0, ws, out);
}

// Round 12
// 899.480 us; speedup vs baseline: 1.3888x; 1.0326x over previous
//
#include <hip/hip_runtime.h>

typedef unsigned short u16;
typedef unsigned char  u8;
typedef signed char    s8;
typedef __bf16 bf16x8 __attribute__((ext_vector_type(8)));
typedef int    i32x4  __attribute__((ext_vector_type(4)));

#define T_STEPS 128
// S2O skewed row: byte offset of feature f = f*2 + (f>>6)*16; row stride 1744 B (872 u16)
#define S2ROW 1744
// HWs skewed row: 560 B per output row
#define HWROW 560

// ---- ws BYTE layout ----
// PK1  @      0 : 16 ft x 5 kt x 1024 =  81920  (Wm0 -> i8 A-frags, 16x16x64)
// PK2  @  81920 : 48 x 5 x 1024      = 245760  (Wf10|Wf20|Wh0)
// PK3  @ 327680 : 16 x 5 x 1024      =  81920  (Wm1, rows permuted)
// BIAS @ 409600 : 1288 f32 (B1[256] B2[768] B3[256] BS[8])
// HW   @ 414752 : 2048 bf16 (head weights [o][k])
//
// Quant: weights w_q = rne(w * 2032); |w|<=1/16 -> |w_q|<=127.
// Activations: cu/c region scale 127 (|v|<1); sn/meas/supd region scale 127/480.
// Epilogue: pre = accA*SA + accB*SB + bias; SA = 0.0625/127^2, SB = 0.5/127^2.

__device__ __forceinline__ float bf2f(u16 h) {
  union { unsigned int u; float f; } v; v.u = ((unsigned int)h) << 16; return v.f;
}
__device__ __forceinline__ u16 f2bf(float f) {
  union { float f; unsigned int u; } v; v.f = f;
  unsigned int u = v.u;
  return (u16)((u + 0x7fffu + ((u >> 16) & 1u)) >> 16);
}
__device__ __forceinline__ unsigned int pack2(float a, float b) {
  return (unsigned int)f2bf(a) | ((unsigned int)f2bf(b) << 16);
}
__device__ __forceinline__ float clampf(float x, float lo, float hi) {
  return fmaxf(lo, fminf(x, hi));   // NaN-absorbing insurance
}
__device__ __forceinline__ float tanh_fast(float x) {
  float e = __expf(2.0f * x);
  return 1.0f - 2.0f * __builtin_amdgcn_rcpf(e + 1.0f);
}
__device__ __forceinline__ int q8(float v, float s) {
  int q = __float2int_rn(v * s);
  return max(-127, min(127, q));
}
__device__ __forceinline__ unsigned int pack4q(float a, float b, float c, float d, float s) {
  return (unsigned int)(q8(a,s) & 255) | ((unsigned int)(q8(b,s) & 255) << 8) |
         ((unsigned int)(q8(c,s) & 255) << 16) | ((unsigned int)(q8(d,s) & 255) << 24);
}
__device__ __forceinline__ s8 qw(float w) {
  int q = __float2int_rn(w * 2032.0f);
  return (s8)max(-127, min(127, q));
}

// i8 MFMA via inline asm (A,B = 4 VGPRs = 16 i8 each; C/D = 4 VGPRs i32)
__device__ __forceinline__ i32x4 mfma_i8(i32x4 a, i32x4 b, i32x4 acc) {
  asm volatile("v_mfma_i32_16x16x64_i8 %0, %1, %2, %0" : "+v"(acc) : "v"(a), "v"(b));
  return acc;
}
// VGPR-tied wait so the compiler can't hoist acc reads above the MFMA pipeline drain
__device__ __forceinline__ i32x4 accfence(i32x4 acc) {
  asm volatile("s_nop 7\n\ts_nop 7" : "+v"(acc));
  return acc;
}

// ---------------- weight repack: f32 -> i8 MFMA A-fragments (runs every call) ----------------
__global__ void egbrnn_prep(
    const float* __restrict__ Wm0, const float* __restrict__ Wm1,
    const float* __restrict__ Wf10, const float* __restrict__ Wf11,
    const float* __restrict__ Wf20, const float* __restrict__ Wf21,
    const float* __restrict__ Wh0, const float* __restrict__ Wh1,
    const float* __restrict__ bm0, const float* __restrict__ bm1,
    const float* __restrict__ bf10, const float* __restrict__ bf11,
    const float* __restrict__ bf20, const float* __restrict__ bf21,
    const float* __restrict__ bh0, const float* __restrict__ bh1,
    u8* __restrict__ ws)
{
  int idx = blockIdx.x * 256 + threadIdx.x;
  // ---- PK1: Wm0, K = [c 0-255 | sn 256-259 | pad] ----
  if (idx < 81920) {
    int tile = idx >> 10, r = idx & 1023;
    int lane = r >> 4, j = r & 15;
    int ft = tile / 5, kt = tile % 5;
    int m = (ft << 4) + (lane & 15);
    int k = kt * 64 + ((lane >> 4) << 4) + j;
    float w = (k < 260) ? Wm0[k * 256 + m] : 0.f;
    ((s8*)ws)[idx] = qw(w);
    return;
  }
  idx -= 81920;
  // ---- PK2: [Wf10|Wf20|Wh0], K = [cu 0-255 | sn 256-259, meas 260-261 | pad] ----
  if (idx < 245760) {
    int tile = idx >> 10, r = idx & 1023;
    int lane = r >> 4, j = r & 15;
    int ft = tile / 5, kt = tile % 5;
    int F = (ft << 4) + (lane & 15);
    int k = kt * 64 + ((lane >> 4) << 4) + j;
    int sel = F >> 8, col = F & 255;
    float w = 0.f;
    if (sel == 0)      { if (k < 260) w = Wf10[k * 256 + col]; }
    else if (sel == 1) { if (k < 260) w = Wf20[k * 256 + col]; }
    else               { if (k < 262) w = Wh0 [k * 256 + col]; }
    ((s8*)ws)[81920 + idx] = qw(w);
    return;
  }
  idx -= 245760;
  // ---- PK3: Wm1; tile4 rows: kk0,1 -> meas rows 256,257; kk2-5 -> supd rows 258-261 ----
  if (idx < 81920) {
    int tile = idx >> 10, r = idx & 1023;
    int lane = r >> 4, j = r & 15;
    int ft = tile / 5, kt = tile % 5;
    int m = (ft << 4) + (lane & 15);
    int row = -1;
    if (kt < 4) row = kt * 64 + ((lane >> 4) << 4) + j;
    else {
      int kk = ((lane >> 4) << 4) + j;
      if (kk < 2) row = 256 + kk;
      else if (kk < 6) row = 258 + (kk - 2);
    }
    float w = (row >= 0) ? Wm1[row * 256 + m] : 0.f;
    ((s8*)ws)[327680 + idx] = qw(w);
    return;
  }
  idx -= 81920;
  // ---- biases (fp32) ----
  if (idx < 1288) {
    float* BIAS = (float*)(ws + 409600);
    float h;
    if (idx < 256) h = bm0[idx];
    else if (idx < 1024) {
      int f = idx - 256;
      h = (f < 256) ? bf10[f] : (f < 512 ? bf20[f - 256] : bh0[f - 512]);
    } else if (idx < 1280) h = bm1[idx - 1024];
    else {
      int i2 = idx - 1280;
      h = (i2 < 2) ? bf11[i2] : (i2 < 6 ? bf21[i2 - 2] : bh1[i2 - 6]);
    }
    BIAS[idx] = h;
    return;
  }
  idx -= 1288;
  // ---- head weights [o][k], bf16 ----
  if (idx < 2048) {
    int o = idx >> 8, k = idx & 255;
    float v;
    if (o < 2)      v = Wf11[k * 2 + o];
    else if (o < 6) v = Wf21[k * 4 + (o - 2)];
    else            v = Wh1[k * 2 + (o - 6)];
    ((u16*)(ws + 414752))[idx] = f2bf(v);
  }
}

// ---------------- main: 128 blocks x 1024 threads (16 waves), 16 batch rows per block ----------------
// R10 structure + (a) PK1 cached in LDS (80 KB, loaded once; cuts streamed weights 400->320 KB/step),
// (b) skewed S2O/HWs layouts (kills the 4-way hpart bank conflicts in the head stage).
__global__ __launch_bounds__(1024, 4) void egbrnn_main(
    const float* __restrict__ x, const float* __restrict__ target,
    const float* __restrict__ c0, const u8* __restrict__ wsp,
    float* __restrict__ out)
{
  // Activations in i8 MFMA B-fragment order: elem (k,n) at tile(k>>6)*1024 + ((k>>4)&3)*256 + n*16 + (k&15)
  __shared__ __align__(16) u8 LPK1[81920];      // stage1 weights, LDS-resident
  __shared__ __align__(16) u8 ACT1[5 * 1024];   // tiles0-3: c/c_new; tile4: sn@kk0-3
  __shared__ __align__(16) u8 ACT2[6 * 1024];   // tiles0-3: cu; tile4a@4096: sn,meas; tile4b@5120: meas,supd
  __shared__ __align__(16) u8 S2O[16 * S2ROW];  // [b][f] bf16 skewed: off = f*2 + (f>>6)*16
  __shared__ __align__(16) u8 HWs[8 * HWROW];   // head weights [o][k] bf16 skewed
  __shared__ __align__(16) float SM[128];       // [b][o]: d0 d1 pv0..3 hv0 hv1

  const float* BIAS = (const float*)(wsp + 409600);
  const float* B1 = BIAS;
  const float* B2 = BIAS + 256;
  const float* B3 = BIAS + 1024;
  const float* BS = BIAS + 1280;

  const float SA = 0.0625f / 16129.0f;   // cu/c region rescale
  const float SB = 0.5f / 16129.0f;      // sn/meas/supd region rescale
  const float SC_SN = 127.0f / 480.0f;   // raw value -> /60 -> x127/8

  const int tid = threadIdx.x;
  const int wave = tid >> 6;     // 0..15
  const int lane = tid & 63;
  const int nidx = lane & 15;
  const int q = lane >> 4;
  const int boff = (q << 8) + (nidx << 4);   // B-frag lane byte offset within a 1 KB tile
  const int loff = lane << 4;                // A-frag lane byte offset
  const int b0 = blockIdx.x << 4;

  // wave-uniform A-frag base pointers (readfirstlane -> SGPR)
  const int wvu = __builtin_amdgcn_readfirstlane(wave);
  const u8* pk2w0 = wsp + 81920 + wvu * 5120;
  const u8* pk2w1 = wsp + 81920 + (wvu + 16) * 5120;
  const u8* pk2w2 = wsp + 81920 + (wvu + 32) * 5120;
  const u8* pk3w  = wsp + 327680 + wvu * 5120;
  const u8* lpk1w = LPK1 + wvu * 5120;

  // ---- PK1 -> LDS (one-time, 5120 x 16B) ----
  for (int i = tid; i < 5120; i += 1024)
    *(i32x4*)(LPK1 + (i << 4)) = *(const i32x4*)(wsp + (i << 4));

  // head weights -> LDS, skewed: byte = o*HWROW + k*2 + (k>>6)*16
  for (int i = tid; i < 2048; i += 1024) {
    int o = i >> 8, k = i & 255;
    *(u16*)(HWs + o * HWROW + (k << 1) + ((k >> 6) << 4)) = ((const u16*)(wsp + 414752))[i];
  }

  // c0 -> ACT1 tiles0-3 (i8, scale 127); thread i writes one u32 (4 consecutive k, one b)
  {
    int p = tid << 2;
    int tile = p >> 10, r = p & 1023;
    int b = (r >> 4) & 15;
    int kg = tile * 64 + ((r >> 8) << 4) + (r & 15);
    float4 cv = *(const float4*)(c0 + (((size_t)(b0 + b)) << 8) + kg);
    *(unsigned int*)(ACT1 + p) = pack4q(cv.x, cv.y, cv.z, cv.w, 127.0f);
  }

  float s0v = 0.f, s1v = 0.f, s2v = 0.f, s3v = 0.f;
  float P[16];
#pragma unroll
  for (int i = 0; i < 16; ++i) P[i] = 0.f;
  if (tid < 16) {
    float4 tg = *(const float4*)(target + (((size_t)(b0 + tid)) << 9));
    s0v = tg.x; s1v = tg.y; s2v = tg.z; s3v = tg.w;
    P[0] = P[5] = P[10] = P[15] = 1.f;
    unsigned int snp = pack4q(s0v, s1v, s2v, s3v, SC_SN);
    *(unsigned int*)(ACT1 + 4096 + (tid << 4)) = snp;
    *(unsigned int*)(ACT2 + 4096 + (tid << 4)) = snp;
  }
  __syncthreads();

  // head assignment: 128 (o,b) pairs x 4 partial lanes (tid < 512)
  const int hpair = tid >> 2, hpart = tid & 3;
  const int hb = hpair & 15, ho = hpair >> 4;
  const int hcolBase = (ho < 2) ? 0 : ((ho < 6) ? 256 : 512);
  const int hf = hcolBase + (hpart << 6);                       // first feature of this partial
  const int hapOff = hb * S2ROW + (hf << 1) + ((hf >> 6) << 4); // skewed S2O byte offset
  const int hwpOff = ho * HWROW + hpart * 144;                  // skewed HWs byte offset

  const i32x4 zero4 = {0, 0, 0, 0};

  for (int t = 0; t < T_STEPS; ++t) {
    // meas_t -> ACT2 tile4a bytes 4,5 (i8)
    if (tid < 16) {
      float2 mm = *(const float2*)(x + (((size_t)(b0 + tid)) << 8) + (t << 1));
      int qm0 = q8(mm.x, SC_SN), qm1 = q8(mm.y, SC_SN);
      *(u16*)(ACT2 + 4096 + (tid << 4) + 4) = (u16)((qm0 & 255) | ((qm1 & 255) << 8));
    }
    // ---- stage1: cu = tanh(Wm0 . [c, sn]); A-frags from LDS ----
    {
      i32x4 aA = zero4, aB = zero4;
#pragma unroll
      for (int kt = 0; kt < 4; ++kt) {
        i32x4 bfr = *(const i32x4*)(ACT1 + (kt << 10) + boff);
        i32x4 af  = *(const i32x4*)(lpk1w + (kt << 10) + loff);
        aA = mfma_i8(af, bfr, aA);
      }
      {
        i32x4 bfr = *(const i32x4*)(ACT1 + 4096 + boff);
        i32x4 af  = *(const i32x4*)(lpk1w + 4096 + loff);
        aB = mfma_i8(af, bfr, aB);
      }
      aA = accfence(aA); aB = accfence(aB);
      const int f0 = (wave << 4) + (q << 2);
      const float4 bs = *(const float4*)(B1 + f0);
      float v0 = tanh_fast(clampf((float)aA[0] * SA + (float)aB[0] * SB + bs.x, -30.f, 30.f));
      float v1 = tanh_fast(clampf((float)aA[1] * SA + (float)aB[1] * SB + bs.y, -30.f, 30.f));
      float v2 = tanh_fast(clampf((float)aA[2] * SA + (float)aB[2] * SB + bs.z, -30.f, 30.f));
      float v3 = tanh_fast(clampf((float)aA[3] * SA + (float)aB[3] * SB + bs.w, -30.f, 30.f));
      *(unsigned int*)(ACT2 + ((f0 >> 6) << 10) + (((f0 >> 4) & 3) << 8) + (nidx << 4) + (f0 & 15)) =
          pack4q(v0, v1, v2, v3, 127.0f);
    }
    __syncthreads();
    // ---- stage2: t1|t2|th; PK2 streams from L2 (15 frags/wave) -> S2O bf16 (skewed) ----
    {
      i32x4 cA[3], cB[3];
#pragma unroll
      for (int i = 0; i < 3; ++i) { cA[i] = zero4; cB[i] = zero4; }
#pragma unroll
      for (int kt = 0; kt < 5; ++kt) {
        i32x4 bfr = *(const i32x4*)(ACT2 + (kt << 10) + boff);   // kt4 -> tile4a @4096
        i32x4 af0 = *(const i32x4*)(pk2w0 + (kt << 10) + loff);
        i32x4 af1 = *(const i32x4*)(pk2w1 + (kt << 10) + loff);
        i32x4 af2 = *(const i32x4*)(pk2w2 + (kt << 10) + loff);
        if (kt < 4) {
          cA[0] = mfma_i8(af0, bfr, cA[0]);
          cA[1] = mfma_i8(af1, bfr, cA[1]);
          cA[2] = mfma_i8(af2, bfr, cA[2]);
        } else {
          cB[0] = mfma_i8(af0, bfr, cB[0]);
          cB[1] = mfma_i8(af1, bfr, cB[1]);
          cB[2] = mfma_i8(af2, bfr, cB[2]);
        }
      }
#pragma unroll
      for (int i = 0; i < 3; ++i) {
        cA[i] = accfence(cA[i]); cB[i] = accfence(cB[i]);
        const int ft = wave + 16 * i;
        const int f0 = (ft << 4) + (q << 2);
        const float4 bs = *(const float4*)(B2 + f0);
        float v0 = tanh_fast(clampf((float)cA[i][0] * SA + (float)cB[i][0] * SB + bs.x, -30.f, 30.f));
        float v1 = tanh_fast(clampf((float)cA[i][1] * SA + (float)cB[i][1] * SB + bs.y, -30.f, 30.f));
        float v2 = tanh_fast(clampf((float)cA[i][2] * SA + (float)cB[i][2] * SB + bs.z, -30.f, 30.f));
        float v3 = tanh_fast(clampf((float)cA[i][3] * SA + (float)cB[i][3] * SB + bs.w, -30.f, 30.f));
        uint2 pv; pv.x = pack2(v0, v1); pv.y = pack2(v2, v3);
        *(uint2*)(S2O + nidx * S2ROW + (f0 << 1) + ((f0 >> 6) << 4)) = pv;
      }
    }
    __syncthreads();
    // ---- small heads: 128 (o,b) bf16 dots of length 256; 4 partial lanes each (skewed, conflict-free) ----
    if (tid < 512) {
      const u8* ap = S2O + hapOff;
      const u8* wp = HWs + hwpOff;
      float p = 0.f;
#pragma unroll
      for (int i = 0; i < 8; ++i) {
        bf16x8 av = *(const bf16x8*)(ap + (i << 4));
        bf16x8 wv = *(const bf16x8*)(wp + (i << 4));
#pragma unroll
        for (int j = 0; j < 8; ++j) p += (float)av[j] * (float)wv[j];
      }
      p += __shfl_xor(p, 1);
      p += __shfl_xor(p, 2);
      if (hpart == 0) SM[hb * 8 + ho] = clampf(p + BS[ho], -64.f, 64.f);
    }
    __syncthreads();
    // ---- Kalman update (lane b owns batch row b; s,P fp32 registers) ----
    if (tid < 16) {
      const float* sm = SM + tid * 8;
      float d0 = sm[0], d1 = sm[1];
      float pv[4] = { sm[2], sm[3], sm[4], sm[5] };
      float hv0 = sm[6], hv1 = sm[7];
      float2 mm = *(const float2*)(x + (((size_t)(b0 + tid)) << 8) + (t << 1));
      float m0 = mm.x, m1 = mm.y;
      float sp[4];
      sp[0] = s0v + s2v + 0.5f * d0;
      sp[1] = s1v + s3v + 0.5f * d1;
      sp[2] = s2v + d0;
      sp[3] = s3v + d1;
      float FP[16], Pp[16];
#pragma unroll
      for (int j = 0; j < 4; ++j) {
        FP[0 * 4 + j] = P[0 * 4 + j] + P[2 * 4 + j];
        FP[1 * 4 + j] = P[1 * 4 + j] + P[3 * 4 + j];
        FP[2 * 4 + j] = P[2 * 4 + j];
        FP[3 * 4 + j] = P[3 * 4 + j];
      }
#pragma unroll
      for (int i = 0; i < 4; ++i) {
        Pp[i * 4 + 0] = FP[i * 4 + 0] + FP[i * 4 + 2];
        Pp[i * 4 + 1] = FP[i * 4 + 1] + FP[i * 4 + 3];
        Pp[i * 4 + 2] = FP[i * 4 + 2];
        Pp[i * 4 + 3] = FP[i * 4 + 3];
      }
#pragma unroll
      for (int i = 0; i < 4; ++i)
#pragma unroll
        for (int j = 0; j < 4; ++j) Pp[i * 4 + j] += pv[i] * pv[j];
#pragma unroll
      for (int i = 0; i < 4; ++i) Pp[i * 4 + i] += 0.01f;
      float in0 = m0 - sp[0], in1 = m1 - sp[1];
      float S00 = Pp[0] + hv0 * hv0 + 1.0f;
      float S01 = Pp[1] + hv0 * hv1;
      float S10 = Pp[4] + hv1 * hv0;
      float S11 = Pp[5] + hv1 * hv1 + 1.0f;
      float det = S00 * S11 - S01 * S10;
      if (!(fabsf(det) > 1e-8f)) det = 1e-8f;
      float idet = 1.0f / det;
      float i00 =  S11 * idet, i01 = -S01 * idet, i10 = -S10 * idet, i11 = S00 * idet;
      float K[8], KS[8], su[4];
#pragma unroll
      for (int i = 0; i < 4; ++i) {
        K[i * 2 + 0] = Pp[i * 4 + 0] * i00 + Pp[i * 4 + 1] * i10;
        K[i * 2 + 1] = Pp[i * 4 + 0] * i01 + Pp[i * 4 + 1] * i11;
      }
#pragma unroll
      for (int i = 0; i < 4; ++i)
        su[i] = clampf(sp[i] + K[i * 2 + 0] * in0 + K[i * 2 + 1] * in1, -131072.f, 131072.f);
#pragma unroll
      for (int i = 0; i < 4; ++i) {
        KS[i * 2 + 0] = K[i * 2 + 0] * S00 + K[i * 2 + 1] * S10;
        KS[i * 2 + 1] = K[i * 2 + 0] * S01 + K[i * 2 + 1] * S11;
      }
#pragma unroll
      for (int i = 0; i < 4; ++i)
#pragma unroll
        for (int j = 0; j < 4; ++j)
          P[i * 4 + j] = clampf(
              Pp[i * 4 + j] - (KS[i * 2 + 0] * K[j * 2 + 0] + KS[i * 2 + 1] * K[j * 2 + 1]),
              -131072.f, 131072.f);
      s0v = su[0]; s1v = su[1]; s2v = su[2]; s3v = su[3];
      // output s_upd (f32)
      float4 ov; ov.x = su[0]; ov.y = su[1]; ov.z = su[2]; ov.w = su[3];
      *(float4*)(out + (((size_t)(b0 + tid)) << 9) + (t << 2)) = ov;
      // sn_{t+1} (ACT1 tile4, ACT2 tile4a) + tile4b [meas0,meas1,supd0..3] (i8)
      unsigned int snp = pack4q(su[0], su[1], su[2], su[3], SC_SN);
      *(unsigned int*)(ACT1 + 4096 + (tid << 4)) = snp;
      *(unsigned int*)(ACT2 + 4096 + (tid << 4)) = snp;
      int qm0 = q8(m0, SC_SN), qm1 = q8(m1, SC_SN);
      *(unsigned int*)(ACT2 + 5120 + (tid << 4)) =
          (unsigned int)(qm0 & 255) | ((unsigned int)(qm1 & 255) << 8) |
          ((snp & 255) << 16) | (((snp >> 8) & 255) << 24);
      *(u16*)(ACT2 + 5120 + (tid << 4) + 4) = (u16)((snp >> 16) & 0xffffu);
    }
    __syncthreads();
    // ---- stage3: c_new = tanh(Wm1 . [cu, meas, supd]) ----
    {
      i32x4 aA = zero4, aB = zero4;
#pragma unroll
      for (int kt = 0; kt < 4; ++kt) {
        i32x4 bfr = *(const i32x4*)(ACT2 + (kt << 10) + boff);
        i32x4 af  = *(const i32x4*)(pk3w + (kt << 10) + loff);
        aA = mfma_i8(af, bfr, aA);
      }
      {
        i32x4 bfr = *(const i32x4*)(ACT2 + 5120 + boff);   // tile4b
        i32x4 af  = *(const i32x4*)(pk3w + 4096 + loff);
        aB = mfma_i8(af, bfr, aB);
      }
      aA = accfence(aA); aB = accfence(aB);
      const int f0 = (wave << 4) + (q << 2);
      const float4 bs = *(const float4*)(B3 + f0);
      float v0 = tanh_fast(clampf((float)aA[0] * SA + (float)aB[0] * SB + bs.x, -30.f, 30.f));
      float v1 = tanh_fast(clampf((float)aA[1] * SA + (float)aB[1] * SB + bs.y, -30.f, 30.f));
      float v2 = tanh_fast(clampf((float)aA[2] * SA + (float)aB[2] * SB + bs.z, -30.f, 30.f));
      float v3 = tanh_fast(clampf((float)aA[3] * SA + (float)aB[3] * SB + bs.w, -30.f, 30.f));
      *(unsigned int*)(ACT1 + ((f0 >> 6) << 10) + (((f0 >> 4) & 3) << 8) + (nidx << 4) + (f0 & 15)) =
          pack4q(v0, v1, v2, v3, 127.0f);
    }
    __syncthreads();
  }
}

extern "C" void kernel_launch(void* const* d_in, const int* in_sizes, int n_in,
                              void* d_out, int out_size, void* d_ws, size_t ws_size,
                              hipStream_t stream) {
  const float* x    = (const float*)d_in[0];
  const float* tgt  = (const float*)d_in[1];
  const float* c0   = (const float*)d_in[2];
  const float* Wm0  = (const float*)d_in[3];
  const float* bm0  = (const float*)d_in[4];
  const float* Wm1  = (const float*)d_in[5];
  const float* bm1  = (const float*)d_in[6];
  const float* Wf10 = (const float*)d_in[7];
  const float* bf10 = (const float*)d_in[8];
  const float* Wf11 = (const float*)d_in[9];
  const float* bf11 = (const float*)d_in[10];
  const float* Wf20 = (const float*)d_in[11];
  const float* bf20 = (const float*)d_in[12];
  const float* Wf21 = (const float*)d_in[13];
  const float* bf21 = (const float*)d_in[14];
  const float* Wh0  = (const float*)d_in[15];
  const float* bh0  = (const float*)d_in[16];
  const float* Wh1  = (const float*)d_in[17];
  const float* bh1  = (const float*)d_in[18];
  u8* ws     = (u8*)d_ws;
  float* out = (float*)d_out;

  // total prep threads: 81920+245760+81920+1288+2048 = 412936
  egbrnn_prep<<<dim3(1614), dim3(256), 0, stream>>>(
      Wm0, Wm1, Wf10, Wf11, Wf20, Wf21, Wh0, Wh1,
      bm0, bm1, bf10, bf11, bf20, bf21, bh0, bh1, ws);
  egbrnn_main<<<dim3(128), dim3(1024), 0, stream>>>(x, tgt, c0, ws, out);
}